// Round 3
// baseline (1098.849 us; speedup 1.0000x reference)
//
#include <hip/hip_runtime.h>
#include <math.h>

#define Bn 4
#define Nn 512
#define Dn 128
#define Hn 64
#define JT 128      // j-tile size
#define NT 4        // Nn / JT

__device__ __forceinline__ float silu_f(float x) {
    return x * (1.0f / (1.0f + __expf(-x)));
}

// ---------------------------------------------------------------------------
// Kernel 1: fused radial MLP + weighting + contraction with neighbor embeds.
// One block per (b,i); 256 threads; j processed in 4 tiles of 128.
//
// amdgpu_waves_per_eu(2,2): LDS (59KB) caps residency at 2 blocks/CU = 2
// waves/EU anyway; pinning min=max=2 gives the allocator the full 256-VGPR
// budget and removes its incentive to spill for unobtainable occupancy.
// (Round 2 evidence: allocator chose 128 VGPRs and spilled ~2.7KB/thread ->
// 2.7 GB/dispatch of HBM scratch traffic.)
// ---------------------------------------------------------------------------
struct __align__(16) K1Smem {
    float rW2t[Hn][68];      // transposed rW2 [k2][k], padded rows, 16B-aligned
    float wh2[JT][68];       // w-scaled LN'd h2 for the current j-tile
    float rW1s[Hn], rb1s[Hn], rg1s[Hn], rb2s[Hn], rg2s[Hn];
    float pS1[2][JT], pS2[2][JT];   // h2-LN partial stats per half
    float wS[JT];            // weight w per row of the tile
    float accA[256], accB[256];     // final cross-thread combine
    int   atomsS[Nn];
};

__global__ __launch_bounds__(256)
__attribute__((amdgpu_waves_per_eu(2, 2)))
void k1_neighbor_feats(const int* __restrict__ atoms,
                       const float* __restrict__ rel_dist,
                       const int* __restrict__ adj_mat,
                       const int* __restrict__ mask,
                       const float* __restrict__ soft,
                       const float* __restrict__ neigh_tab,
                       const float* __restrict__ rW1, const float* __restrict__ rb1,
                       const float* __restrict__ rg1,
                       const float* __restrict__ rW2, const float* __restrict__ rb2,
                       const float* __restrict__ rg2,
                       const float* __restrict__ rW3, const float* __restrict__ rb3,
                       float* __restrict__ nf)
{
    __shared__ K1Smem sm;
    const int t  = threadIdx.x;
    const int bi = blockIdx.x;      // b*N + i
    const int b  = bi >> 9;
    const int i  = bi & 511;

    // ---- stage weights ----
    for (int idx = t; idx < Hn * Hn; idx += 256) {
        sm.rW2t[idx & 63][idx >> 6] = rW2[idx];   // rW2t[k2][k] = rW2[k][k2]
    }
    if (t < Hn) {
        sm.rW1s[t] = rW1[t];
        sm.rb1s[t] = rb1[t];
        sm.rg1s[t] = rg1[t];
        sm.rb2s[t] = rb2[t];
        sm.rg2s[t] = rg2[t];
    }
    for (int j = t; j < Nn; j += 256) sm.atomsS[j] = atoms[b * Nn + j];

    // phase-A mapping
    const int jloc = t & 127;
    const int half = t >> 7;
    // phase-B mapping
    const int d2 = t & 63;          // output column pair {2*d2, 2*d2+1}
    const int kh = (t >> 6) & 1;    // k-slice
    const int jh = t >> 7;          // row-half
    const float2 rb3v  = *(const float2*)&rb3[2 * d2];
    const float  rb3e0 = (kh == 0) ? rb3v.x : 0.0f;   // bias counted once per (j,d)
    const float  rb3e1 = (kh == 0) ? rb3v.y : 0.0f;
    const int rowbase = bi * Nn;

    float acc0 = 0.0f, acc1 = 0.0f;
    __syncthreads();

    for (int jt = 0; jt < NT; ++jt) {
        const int jme = jt * JT + jloc;

        // ---- phase A ----
        const float dist = rel_dist[rowbase + jme];
        const int   adjv = adj_mat[rowbase + jme];
        const int   mk   = mask[b * Nn + jme];
        const float w = (adjv != 0 && mk != 0 && jme != i) ? soft[rowbase + jme] : 0.0f;

        // layer 1: silu(dist*rW1 + rb1) then LN(rg1)  (full 64, both halves)
        float h1n[Hn];
        float s1 = 0.f, s2 = 0.f;
        #pragma unroll
        for (int k = 0; k < Hn; ++k) {
            const float v = silu_f(dist * sm.rW1s[k] + sm.rb1s[k]);
            h1n[k] = v; s1 += v; s2 += v * v;
        }
        float m  = s1 * (1.0f / 64.0f);
        float vr = s2 * (1.0f / 64.0f) - m * m;
        float rs = rsqrtf(vr + 1e-5f);
        #pragma unroll
        for (int k = 0; k < Hn; ++k) h1n[k] = (h1n[k] - m) * rs * sm.rg1s[k];

        // layer 2 (my 32-wide half of k2): silu(h1n @ rW2 + rb2)
        float h2[32];
        float t1 = 0.f, t2 = 0.f;
        #pragma unroll
        for (int k2 = 0; k2 < 32; ++k2) {
            const int kk2 = half * 32 + k2;
            float p0 = 0.f, p1 = 0.f, p2 = 0.f, p3 = 0.f;
            #pragma unroll
            for (int k = 0; k < Hn; k += 4) {
                const float4 wv = *(const float4*)&sm.rW2t[kk2][k];  // broadcast
                p0 += h1n[k + 0] * wv.x;
                p1 += h1n[k + 1] * wv.y;
                p2 += h1n[k + 2] * wv.z;
                p3 += h1n[k + 3] * wv.w;
            }
            const float v = silu_f((p0 + p1) + (p2 + p3) + sm.rb2s[kk2]);
            h2[k2] = v; t1 += v; t2 += v * v;
        }
        // combine LN stats across the half-pair
        sm.pS1[half][jloc] = t1;
        sm.pS2[half][jloc] = t2;
        if (half == 0) sm.wS[jloc] = w;
        __syncthreads();
        const float T1 = sm.pS1[0][jloc] + sm.pS1[1][jloc];
        const float T2 = sm.pS2[0][jloc] + sm.pS2[1][jloc];
        m  = T1 * (1.0f / 64.0f);
        vr = T2 * (1.0f / 64.0f) - m * m;
        rs = rsqrtf(vr + 1e-5f);
        #pragma unroll
        for (int k2 = 0; k2 < 32; k2 += 4) {
            const int kk2 = half * 32 + k2;
            float4 ov;
            ov.x = w * ((h2[k2 + 0] - m) * rs * sm.rg2s[kk2 + 0]);
            ov.y = w * ((h2[k2 + 1] - m) * rs * sm.rg2s[kk2 + 1]);
            ov.z = w * ((h2[k2 + 2] - m) * rs * sm.rg2s[kk2 + 2]);
            ov.w = w * ((h2[k2 + 3] - m) * rs * sm.rg2s[kk2 + 3]);
            *(float4*)&sm.wh2[jloc][kk2] = ov;
        }
        __syncthreads();

        // ---- phase B: contraction over the tile ----
        // (h1n/h2 dead here; rW3 slice loaded now to keep peak VGPR low)
        float rw3a[32], rw3b[32];
        #pragma unroll
        for (int k = 0; k < 32; ++k) {
            const float2 rv = *(const float2*)&rW3[(kh * 32 + k) * Dn + 2 * d2];
            rw3a[k] = rv.x; rw3b[k] = rv.y;
        }
        #pragma unroll 4
        for (int jj = 0; jj < 64; ++jj) {
            const int lr = jh * 64 + jj;
            const int j  = jt * JT + lr;
            float pa0 = 0.f, pa1 = 0.f, pa2 = 0.f, pa3 = 0.f;
            float pb0 = 0.f, pb1 = 0.f, pb2 = 0.f, pb3 = 0.f;
            #pragma unroll
            for (int k = 0; k < 32; k += 4) {
                const float4 hv = *(const float4*)&sm.wh2[lr][kh * 32 + k];  // broadcast
                pa0 += hv.x * rw3a[k + 0];
                pa1 += hv.y * rw3a[k + 1];
                pa2 += hv.z * rw3a[k + 2];
                pa3 += hv.w * rw3a[k + 3];
                pb0 += hv.x * rw3b[k + 0];
                pb1 += hv.y * rw3b[k + 1];
                pb2 += hv.z * rw3b[k + 2];
                pb3 += hv.w * rw3b[k + 3];
            }
            const float  wj = sm.wS[lr];
            const float2 nv = *(const float2*)&neigh_tab[sm.atomsS[j] * Dn + 2 * d2];
            acc0 += (((pa0 + pa1) + (pa2 + pa3)) + wj * rb3e0) * nv.x;
            acc1 += (((pb0 + pb1) + (pb2 + pb3)) + wj * rb3e1) * nv.y;
        }
        __syncthreads();   // protect wh2/pS/wS for next tile
    }

    // ---- final cross-thread combine: out d gets 4 partials ----
    sm.accA[t] = acc0;
    sm.accB[t] = acc1;
    __syncthreads();
    if (t < Dn) {
        const int  dd2 = t >> 1;
        const bool odd = (t & 1) != 0;
        float r = 0.f;
        #pragma unroll
        for (int q = 0; q < 4; ++q) {
            const int src = dd2 + 64 * (q & 1) + 128 * (q >> 1);  // d2 + 64*kh + 128*jh
            r += odd ? sm.accB[src] : sm.accA[src];
        }
        nf[bi * Dn + t] = r;
    }
}

// ---------------------------------------------------------------------------
// Kernel 2: node MLP.  x = [embeds, nf] (256) -> Linear -> LN -> silu -> Linear
// One block per (b,i); 128 threads (one per output d).
// ---------------------------------------------------------------------------
__global__ __launch_bounds__(128)
void k2_node_mlp(const int* __restrict__ atoms,
                 const float* __restrict__ atom_tab,
                 const float* __restrict__ nf,
                 const float* __restrict__ nW1, const float* __restrict__ nb1,
                 const float* __restrict__ ng,
                 const float* __restrict__ nW2, const float* __restrict__ nb2,
                 float* __restrict__ out)
{
    __shared__ float xs[256];
    __shared__ float r1[2], r2[2];
    __shared__ float x2[128];

    const int t  = threadIdx.x;
    const int bi = blockIdx.x;
    const int a  = atoms[bi];

    xs[t]       = atom_tab[a * Dn + t];
    xs[128 + t] = nf[bi * Dn + t];
    __syncthreads();

    float p0 = 0.f, p1 = 0.f, p2 = 0.f, p3 = 0.f;
    #pragma unroll 4
    for (int c = 0; c < 256; c += 4) {
        p0 += xs[c + 0] * nW1[(c + 0) * Dn + t];
        p1 += xs[c + 1] * nW1[(c + 1) * Dn + t];
        p2 += xs[c + 2] * nW1[(c + 2) * Dn + t];
        p3 += xs[c + 3] * nW1[(c + 3) * Dn + t];
    }
    const float s = (p0 + p1) + (p2 + p3) + nb1[t];

    // LN over 128 (2 waves): wave shuffle reduce + LDS combine
    float a1 = s, a2 = s * s;
    #pragma unroll
    for (int off = 32; off > 0; off >>= 1) {
        a1 += __shfl_down(a1, off);
        a2 += __shfl_down(a2, off);
    }
    const int wid = t >> 6;
    if ((t & 63) == 0) { r1[wid] = a1; r2[wid] = a2; }
    __syncthreads();
    const float S1 = r1[0] + r1[1];
    const float S2 = r2[0] + r2[1];
    const float m  = S1 * (1.0f / 128.0f);
    const float vr = S2 * (1.0f / 128.0f) - m * m;
    const float rs = rsqrtf(vr + 1e-5f);
    const float y  = silu_f((s - m) * rs * ng[t]);   // LN first, THEN silu

    x2[t] = y;
    __syncthreads();

    float q0 = 0.f, q1 = 0.f, q2 = 0.f, q3 = 0.f;
    #pragma unroll 4
    for (int c = 0; c < 128; c += 4) {
        q0 += x2[c + 0] * nW2[(c + 0) * Dn + t];
        q1 += x2[c + 1] * nW2[(c + 1) * Dn + t];
        q2 += x2[c + 2] * nW2[(c + 2) * Dn + t];
        q3 += x2[c + 3] * nW2[(c + 3) * Dn + t];
    }
    out[bi * Dn + t] = (q0 + q1) + (q2 + q3) + nb2[t];
}

// ---------------------------------------------------------------------------
extern "C" void kernel_launch(void* const* d_in, const int* in_sizes, int n_in,
                              void* d_out, int out_size, void* d_ws, size_t ws_size,
                              hipStream_t stream)
{
    (void)in_sizes; (void)n_in; (void)out_size; (void)ws_size;

    const int*   atoms = (const int*)d_in[0];
    const float* rel   = (const float*)d_in[1];
    const int*   adj   = (const int*)d_in[2];
    const int*   mask  = (const int*)d_in[3];
    const float* soft  = (const float*)d_in[4];
    const float* atab  = (const float*)d_in[5];
    const float* ntab  = (const float*)d_in[6];
    const float* rW1   = (const float*)d_in[7];
    const float* rb1   = (const float*)d_in[8];
    const float* rg1   = (const float*)d_in[9];
    const float* rW2   = (const float*)d_in[10];
    const float* rb2   = (const float*)d_in[11];
    const float* rg2   = (const float*)d_in[12];
    const float* rW3   = (const float*)d_in[13];
    const float* rb3   = (const float*)d_in[14];
    const float* nW1   = (const float*)d_in[15];
    const float* nb1   = (const float*)d_in[16];
    const float* ng    = (const float*)d_in[17];
    const float* nW2   = (const float*)d_in[18];
    const float* nb2   = (const float*)d_in[19];

    float* nf  = (float*)d_ws;      // [B*N, D] neighbor feats scratch (1 MB)
    float* out = (float*)d_out;

    hipLaunchKernelGGL(k1_neighbor_feats, dim3(Bn * Nn), dim3(256), 0, stream,
                       atoms, rel, adj, mask, soft, ntab,
                       rW1, rb1, rg1, rW2, rb2, rg2, rW3, rb3, nf);
    hipLaunchKernelGGL(k2_node_mlp, dim3(Bn * Nn), dim3(128), 0, stream,
                       atoms, atab, nf, nW1, nb1, ng, nW2, nb2, out);
}

// Round 4
// 155.643 us; speedup vs baseline: 7.0601x; 7.0601x over previous
//
#include <hip/hip_runtime.h>
#include <hip/hip_bf16.h>
#include <math.h>

#define Bn 4
#define Nn 512
#define Dn 128
#define Hn 64

__device__ __forceinline__ float silu_f(float x) {
    return x * (1.0f / (1.0f + __expf(-x)));
}

// ---------------------------------------------------------------------------
// k0: tabulate the radial MLP  G(x) : scalar -> R^128  at x = t/T, t=0..T.
// One wave (64 threads) per table entry; LN via 64-lane butterflies.
// rel_dist ~ U[0,1), so [0,1] covers the full input domain.
// ---------------------------------------------------------------------------
__global__ __launch_bounds__(64)
void k0_build_table(const float* __restrict__ rW1, const float* __restrict__ rb1,
                    const float* __restrict__ rg1,
                    const float* __restrict__ rW2, const float* __restrict__ rb2,
                    const float* __restrict__ rg2,
                    const float* __restrict__ rW3, const float* __restrict__ rb3,
                    int T, __hip_bfloat16* __restrict__ table)
{
    __shared__ float h1s[Hn];
    __shared__ float h2s[Hn];
    const int te = blockIdx.x;          // table entry 0..T
    const int k  = threadIdx.x;         // 0..63
    const float x = (float)te / (float)T;

    // layer 1: silu(x*rW1 + rb1), LN(rg1)   (biased variance, eps 1e-5)
    float h = silu_f(x * rW1[k] + rb1[k]);
    float s1 = h, s2 = h * h;
    #pragma unroll
    for (int m = 1; m < 64; m <<= 1) {
        s1 += __shfl_xor(s1, m);
        s2 += __shfl_xor(s2, m);
    }
    float mean = s1 * (1.0f / 64.0f);
    float var  = s2 * (1.0f / 64.0f) - mean * mean;
    float rs   = rsqrtf(var + 1e-5f);
    h1s[k] = (h - mean) * rs * rg1[k];
    __syncthreads();

    // layer 2: silu(h1n @ rW2 + rb2), LN(rg2)
    float p = 0.f;
    #pragma unroll 8
    for (int kk = 0; kk < Hn; ++kk) p += h1s[kk] * rW2[kk * Hn + k];
    float h2 = silu_f(p + rb2[k]);
    s1 = h2; s2 = h2 * h2;
    #pragma unroll
    for (int m = 1; m < 64; m <<= 1) {
        s1 += __shfl_xor(s1, m);
        s2 += __shfl_xor(s2, m);
    }
    mean = s1 * (1.0f / 64.0f);
    var  = s2 * (1.0f / 64.0f) - mean * mean;
    rs   = rsqrtf(var + 1e-5f);
    h2s[k] = (h2 - mean) * rs * rg2[k];
    __syncthreads();

    // layer 3: h2n @ rW3 + rb3  ->  bf16 table row
    #pragma unroll
    for (int dd = 0; dd < 2; ++dd) {
        const int d = dd * 64 + k;
        float f = rb3[d];
        #pragma unroll 8
        for (int kk = 0; kk < Hn; ++kk) f += h2s[kk] * rW3[kk * Dn + d];
        table[te * Dn + d] = __float2bfloat16(f);
    }
}

// ---------------------------------------------------------------------------
// k1: nf[b,i,d] = sum_j w(b,i,j) * lerp_d(table, dist) * ntab[atoms[b,j], d]
// Block per (b,i); 256 threads: lane-pair owns d0={2dl,2dl+1}, jq = j-quarter.
// All per-j scalars are wave-uniform -> w==0 skip is divergence-free (~50%).
// No per-thread arrays anywhere -> no scratch (rounds 1-3 lost 2.8 GB/launch
// to scratch churn from demoted arrays).
// ---------------------------------------------------------------------------
struct K1S {
    float fr[Nn];
    float ws[Nn];
    int   i0[Nn];
    int   at[Nn];
    float accs[4][64][2];
};

__global__ __launch_bounds__(256)
void k1_contract(const int* __restrict__ atoms, const float* __restrict__ rel,
                 const int* __restrict__ adj, const int* __restrict__ mask,
                 const float* __restrict__ soft, const float* __restrict__ ntab,
                 const __hip_bfloat16* __restrict__ table, int T,
                 float* __restrict__ nf)
{
    __shared__ K1S sm;
    const int t  = threadIdx.x;
    const int bi = blockIdx.x;          // b*N + i
    const int b  = bi >> 9;
    const int i  = bi & 511;
    const int rowbase = bi * Nn;

    // stage per-j scalars
    for (int j = t; j < Nn; j += 256) {
        const float dist = rel[rowbase + j];
        const int   adjv = adj[rowbase + j];
        const int   mk   = mask[b * Nn + j];
        const float w = (adjv != 0 && mk != 0 && j != i) ? soft[rowbase + j] : 0.0f;
        float xx = dist * (float)T;
        int   xi = (int)xx;
        xi = min(max(xi, 0), T - 1);
        sm.fr[j] = xx - (float)xi;
        sm.ws[j] = w;
        sm.i0[j] = xi;
        sm.at[j] = atoms[b * Nn + j];
    }
    __syncthreads();

    const int dl = t & 63;
    const int d0 = dl * 2;
    const int jq = t >> 6;
    float a0 = 0.f, a1 = 0.f;

    for (int jj = 0; jj < 128; ++jj) {
        const int   j = jq * 128 + jj;
        const float w = sm.ws[j];            // broadcast, wave-uniform
        if (w == 0.0f) continue;             // exec-mask skip, whole wave
        const int   i0 = sm.i0[j];
        const float f  = sm.fr[j];
        const int   a  = sm.at[j];
        const __hip_bfloat162 t0 = *(const __hip_bfloat162*)&table[i0 * Dn + d0];
        const __hip_bfloat162 t1 = *(const __hip_bfloat162*)&table[(i0 + 1) * Dn + d0];
        const float2 nv = *(const float2*)&ntab[a * Dn + d0];
        const float v00 = __bfloat162float(t0.x), v01 = __bfloat162float(t0.y);
        const float v10 = __bfloat162float(t1.x), v11 = __bfloat162float(t1.y);
        const float val0 = v00 + f * (v10 - v00);
        const float val1 = v01 + f * (v11 - v01);
        a0 += (w * nv.x) * val0;
        a1 += (w * nv.y) * val1;
    }
    sm.accs[jq][dl][0] = a0;
    sm.accs[jq][dl][1] = a1;
    __syncthreads();
    if (t < Dn) {
        float r = 0.f;
        #pragma unroll
        for (int q = 0; q < 4; ++q) r += sm.accs[q][t >> 1][t & 1];
        nf[bi * Dn + t] = r;
    }
}

// ---------------------------------------------------------------------------
// k2: node MLP.  x = [embeds, nf] (256) -> Linear -> LN -> silu -> Linear
// One block per (b,i); 128 threads (one per output d).  (verified r1-r3)
// ---------------------------------------------------------------------------
__global__ __launch_bounds__(128)
void k2_node_mlp(const int* __restrict__ atoms,
                 const float* __restrict__ atom_tab,
                 const float* __restrict__ nf,
                 const float* __restrict__ nW1, const float* __restrict__ nb1,
                 const float* __restrict__ ng,
                 const float* __restrict__ nW2, const float* __restrict__ nb2,
                 float* __restrict__ out)
{
    __shared__ float xs[256];
    __shared__ float r1[2], r2[2];
    __shared__ float x2[128];

    const int t  = threadIdx.x;
    const int bi = blockIdx.x;
    const int a  = atoms[bi];

    xs[t]       = atom_tab[a * Dn + t];
    xs[128 + t] = nf[bi * Dn + t];
    __syncthreads();

    float p0 = 0.f, p1 = 0.f, p2 = 0.f, p3 = 0.f;
    #pragma unroll 4
    for (int c = 0; c < 256; c += 4) {
        p0 += xs[c + 0] * nW1[(c + 0) * Dn + t];
        p1 += xs[c + 1] * nW1[(c + 1) * Dn + t];
        p2 += xs[c + 2] * nW1[(c + 2) * Dn + t];
        p3 += xs[c + 3] * nW1[(c + 3) * Dn + t];
    }
    const float s = (p0 + p1) + (p2 + p3) + nb1[t];

    float a1 = s, a2 = s * s;
    #pragma unroll
    for (int off = 32; off > 0; off >>= 1) {
        a1 += __shfl_down(a1, off);
        a2 += __shfl_down(a2, off);
    }
    const int wid = t >> 6;
    if ((t & 63) == 0) { r1[wid] = a1; r2[wid] = a2; }
    __syncthreads();
    const float S1 = r1[0] + r1[1];
    const float S2 = r2[0] + r2[1];
    const float m  = S1 * (1.0f / 128.0f);
    const float vr = S2 * (1.0f / 128.0f) - m * m;
    const float rs = rsqrtf(vr + 1e-5f);
    const float y  = silu_f((s - m) * rs * ng[t]);   // LN first, THEN silu

    x2[t] = y;
    __syncthreads();

    float q0 = 0.f, q1 = 0.f, q2 = 0.f, q3 = 0.f;
    #pragma unroll 4
    for (int c = 0; c < 128; c += 4) {
        q0 += x2[c + 0] * nW2[(c + 0) * Dn + t];
        q1 += x2[c + 1] * nW2[(c + 1) * Dn + t];
        q2 += x2[c + 2] * nW2[(c + 2) * Dn + t];
        q3 += x2[c + 3] * nW2[(c + 3) * Dn + t];
    }
    out[bi * Dn + t] = (q0 + q1) + (q2 + q3) + nb2[t];
}

// ---------------------------------------------------------------------------
extern "C" void kernel_launch(void* const* d_in, const int* in_sizes, int n_in,
                              void* d_out, int out_size, void* d_ws, size_t ws_size,
                              hipStream_t stream)
{
    (void)in_sizes; (void)n_in; (void)out_size;

    const int*   atoms = (const int*)d_in[0];
    const float* rel   = (const float*)d_in[1];
    const int*   adj   = (const int*)d_in[2];
    const int*   mask  = (const int*)d_in[3];
    const float* soft  = (const float*)d_in[4];
    const float* atab  = (const float*)d_in[5];
    const float* ntab  = (const float*)d_in[6];
    const float* rW1   = (const float*)d_in[7];
    const float* rb1   = (const float*)d_in[8];
    const float* rg1   = (const float*)d_in[9];
    const float* rW2   = (const float*)d_in[10];
    const float* rb2   = (const float*)d_in[11];
    const float* rg2   = (const float*)d_in[12];
    const float* rW3   = (const float*)d_in[13];
    const float* rb3   = (const float*)d_in[14];
    const float* nW1   = (const float*)d_in[15];
    const float* nb1   = (const float*)d_in[16];
    const float* ng    = (const float*)d_in[17];
    const float* nW2   = (const float*)d_in[18];
    const float* nb2   = (const float*)d_in[19];

    // workspace layout: nf (1 MB f32) | table ((T+1) x 128 bf16)
    char*  wsc = (char*)d_ws;
    float* nf  = (float*)wsc;
    const size_t nfB = (size_t)Bn * Nn * Dn * sizeof(float);
    __hip_bfloat16* table = (__hip_bfloat16*)(wsc + nfB);
    const size_t avail = (ws_size > nfB) ? (ws_size - nfB) : 0;
    int T;
    if      (avail >= (size_t)2049 * Dn * 2) T = 2048;
    else if (avail >= (size_t)1025 * Dn * 2) T = 1024;
    else                                     T = 256;

    float* out = (float*)d_out;

    hipLaunchKernelGGL(k0_build_table, dim3(T + 1), dim3(64), 0, stream,
                       rW1, rb1, rg1, rW2, rb2, rg2, rW3, rb3, T, table);
    hipLaunchKernelGGL(k1_contract, dim3(Bn * Nn), dim3(256), 0, stream,
                       atoms, rel, adj, mask, soft, ntab, table, T, nf);
    hipLaunchKernelGGL(k2_node_mlp, dim3(Bn * Nn), dim3(128), 0, stream,
                       atoms, atab, nf, nW1, nb1, ng, nW2, nb2, out);
}

// Round 6
// 150.715 us; speedup vs baseline: 7.2909x; 1.0327x over previous
//
#include <hip/hip_runtime.h>
#include <hip/hip_bf16.h>
#include <math.h>

#define Bn 4
#define Nn 512
#define Dn 128
#define Hn 64
#define TT 2048

__device__ __forceinline__ float silu_f(float x) {
    return x * (1.0f / (1.0f + __expf(-x)));
}

// ---------------------------------------------------------------------------
// k0: tabulate the radial MLP  G(x) : scalar -> R^128  at x = te/TT.
// One wave per table entry; LN via 64-lane butterflies.  (verified round 4)
// ---------------------------------------------------------------------------
__global__ __launch_bounds__(64)
void k0_build_table(const float* __restrict__ rW1, const float* __restrict__ rb1,
                    const float* __restrict__ rg1,
                    const float* __restrict__ rW2, const float* __restrict__ rb2,
                    const float* __restrict__ rg2,
                    const float* __restrict__ rW3, const float* __restrict__ rb3,
                    __hip_bfloat16* __restrict__ table)
{
    __shared__ float h1s[Hn];
    __shared__ float h2s[Hn];
    const int te = blockIdx.x;          // 0..TT
    const int k  = threadIdx.x;         // 0..63
    const float x = (float)te / (float)TT;

    float h = silu_f(x * rW1[k] + rb1[k]);
    float s1 = h, s2 = h * h;
    #pragma unroll
    for (int m = 1; m < 64; m <<= 1) { s1 += __shfl_xor(s1, m); s2 += __shfl_xor(s2, m); }
    float mean = s1 * (1.0f / 64.0f);
    float var  = s2 * (1.0f / 64.0f) - mean * mean;
    float rs   = rsqrtf(var + 1e-5f);
    h1s[k] = (h - mean) * rs * rg1[k];
    __syncthreads();

    float p = 0.f;
    #pragma unroll 8
    for (int kk = 0; kk < Hn; ++kk) p += h1s[kk] * rW2[kk * Hn + k];
    float h2 = silu_f(p + rb2[k]);
    s1 = h2; s2 = h2 * h2;
    #pragma unroll
    for (int m = 1; m < 64; m <<= 1) { s1 += __shfl_xor(s1, m); s2 += __shfl_xor(s2, m); }
    mean = s1 * (1.0f / 64.0f);
    var  = s2 * (1.0f / 64.0f) - mean * mean;
    rs   = rsqrtf(var + 1e-5f);
    h2s[k] = (h2 - mean) * rs * rg2[k];
    __syncthreads();

    #pragma unroll
    for (int dd = 0; dd < 2; ++dd) {
        const int d = dd * 64 + k;
        float f = rb3[d];
        #pragma unroll 8
        for (int kk = 0; kk < Hn; ++kk) f += h2s[kk] * rW3[kk * Dn + d];
        table[te * Dn + d] = __float2bfloat16(f);
    }
}

// ---------------------------------------------------------------------------
// k1: fused contraction + node MLP.  Block per (b,i), 256 threads.
//   Stage 1 (R4-verified): nf_row[d] = sum_j w * lerp_d(table,dist) * ntab[a_j,d]
//   Stage 2 (R4-verified k2 logic, fused): out = (silu(LN([emb,nf]@nW1+nb1,ng)))@nW2+nb2
// Fusion removes the k2 launch and the nf HBM round-trip; barriers are
// unconditional (all 256 threads), compute guarded to t<128.
// ---------------------------------------------------------------------------
struct K1S {
    float fr[Nn];
    float ws[Nn];
    int   i0[Nn];
    int   at[Nn];
    float accs[4][64][2];
    float xs[256];
    float r1[2], r2[2];
    float x2[128];
};

__global__ __launch_bounds__(256)
void k1_fused(const int* __restrict__ atoms, const float* __restrict__ rel,
              const int* __restrict__ adj, const int* __restrict__ mask,
              const float* __restrict__ soft, const float* __restrict__ ntab,
              const __hip_bfloat16* __restrict__ table,
              const float* __restrict__ atom_tab,
              const float* __restrict__ nW1, const float* __restrict__ nb1,
              const float* __restrict__ ng,
              const float* __restrict__ nW2, const float* __restrict__ nb2,
              float* __restrict__ out)
{
    __shared__ K1S sm;
    const int t  = threadIdx.x;
    const int bi = blockIdx.x;          // b*N + i
    const int b  = bi >> 9;
    const int i  = bi & 511;
    const int rowbase = bi * Nn;

    // ---- stage per-j scalars (identical to round-4 verified kernel) ----
    for (int j = t; j < Nn; j += 256) {
        const float dist = rel[rowbase + j];
        const int   adjv = adj[rowbase + j];
        const int   mk   = mask[b * Nn + j];
        const float w = (adjv != 0 && mk != 0 && j != i) ? soft[rowbase + j] : 0.0f;
        float xx = dist * (float)TT;
        int   xi = (int)xx;
        xi = min(max(xi, 0), TT - 1);
        sm.fr[j] = xx - (float)xi;
        sm.ws[j] = w;
        sm.i0[j] = xi;
        sm.at[j] = atoms[b * Nn + j];
    }
    __syncthreads();

    const int dl = t & 63;
    const int d0 = dl * 2;
    const int jq = t >> 6;
    float a0 = 0.f, a1 = 0.f;

    for (int jj = 0; jj < 128; ++jj) {
        const int   j = jq * 128 + jj;
        const float w = sm.ws[j];            // broadcast, wave-uniform
        if (w == 0.0f) continue;             // exec-mask skip, whole wave
        const int   i0 = sm.i0[j];
        const float f  = sm.fr[j];
        const int   a  = sm.at[j];
        const __hip_bfloat162 t0 = *(const __hip_bfloat162*)&table[i0 * Dn + d0];
        const __hip_bfloat162 t1 = *(const __hip_bfloat162*)&table[(i0 + 1) * Dn + d0];
        const float2 nv = *(const float2*)&ntab[a * Dn + d0];
        const float v00 = __bfloat162float(t0.x), v01 = __bfloat162float(t0.y);
        const float v10 = __bfloat162float(t1.x), v11 = __bfloat162float(t1.y);
        const float val0 = v00 + f * (v10 - v00);
        const float val1 = v01 + f * (v11 - v01);
        a0 += (w * nv.x) * val0;
        a1 += (w * nv.y) * val1;
    }
    sm.accs[jq][dl][0] = a0;
    sm.accs[jq][dl][1] = a1;
    __syncthreads();

    // ---- fused node-MLP epilogue (round-4 verified k2 logic) ----
    const int a = atoms[bi];
    if (t < Dn) {
        float r = 0.f;
        #pragma unroll
        for (int q = 0; q < 4; ++q) r += sm.accs[q][t >> 1][t & 1];
        sm.xs[t]       = atom_tab[a * Dn + t];
        sm.xs[128 + t] = r;
    }
    __syncthreads();

    float s = 0.f;
    if (t < Dn) {
        float p0 = 0.f, p1 = 0.f, p2 = 0.f, p3 = 0.f;
        #pragma unroll 4
        for (int c = 0; c < 256; c += 4) {
            p0 += sm.xs[c + 0] * nW1[(c + 0) * Dn + t];
            p1 += sm.xs[c + 1] * nW1[(c + 1) * Dn + t];
            p2 += sm.xs[c + 2] * nW1[(c + 2) * Dn + t];
            p3 += sm.xs[c + 3] * nW1[(c + 3) * Dn + t];
        }
        s = (p0 + p1) + (p2 + p3) + nb1[t];
        float a1r = s, a2r = s * s;
        #pragma unroll
        for (int off = 32; off > 0; off >>= 1) {
            a1r += __shfl_down(a1r, off);
            a2r += __shfl_down(a2r, off);
        }
        if ((t & 63) == 0) { sm.r1[t >> 6] = a1r; sm.r2[t >> 6] = a2r; }
    }
    __syncthreads();

    if (t < Dn) {
        const float S1 = sm.r1[0] + sm.r1[1];
        const float S2 = sm.r2[0] + sm.r2[1];
        const float m  = S1 * (1.0f / 128.0f);
        const float vr = S2 * (1.0f / 128.0f) - m * m;
        const float rs = rsqrtf(vr + 1e-5f);
        sm.x2[t] = silu_f((s - m) * rs * ng[t]);   // LN first, THEN silu
    }
    __syncthreads();

    if (t < Dn) {
        float q0 = 0.f, q1 = 0.f, q2 = 0.f, q3 = 0.f;
        #pragma unroll 4
        for (int c = 0; c < 128; c += 4) {
            q0 += sm.x2[c + 0] * nW2[(c + 0) * Dn + t];
            q1 += sm.x2[c + 1] * nW2[(c + 1) * Dn + t];
            q2 += sm.x2[c + 2] * nW2[(c + 2) * Dn + t];
            q3 += sm.x2[c + 3] * nW2[(c + 3) * Dn + t];
        }
        out[bi * Dn + t] = (q0 + q1) + (q2 + q3) + nb2[t];
    }
}

// ---------------------------------------------------------------------------
extern "C" void kernel_launch(void* const* d_in, const int* in_sizes, int n_in,
                              void* d_out, int out_size, void* d_ws, size_t ws_size,
                              hipStream_t stream)
{
    (void)in_sizes; (void)n_in; (void)out_size; (void)ws_size;

    const int*   atoms = (const int*)d_in[0];
    const float* rel   = (const float*)d_in[1];
    const int*   adj   = (const int*)d_in[2];
    const int*   mask  = (const int*)d_in[3];
    const float* soft  = (const float*)d_in[4];
    const float* atab  = (const float*)d_in[5];
    const float* ntab  = (const float*)d_in[6];
    const float* rW1   = (const float*)d_in[7];
    const float* rb1   = (const float*)d_in[8];
    const float* rg1   = (const float*)d_in[9];
    const float* rW2   = (const float*)d_in[10];
    const float* rb2   = (const float*)d_in[11];
    const float* rg2   = (const float*)d_in[12];
    const float* rW3   = (const float*)d_in[13];
    const float* rb3   = (const float*)d_in[14];
    const float* nW1   = (const float*)d_in[15];
    const float* nb1   = (const float*)d_in[16];
    const float* ng    = (const float*)d_in[17];
    const float* nW2   = (const float*)d_in[18];
    const float* nb2   = (const float*)d_in[19];

    __hip_bfloat16* table = (__hip_bfloat16*)d_ws;   // (TT+1) x 128 bf16
    float* out = (float*)d_out;

    hipLaunchKernelGGL(k0_build_table, dim3(TT + 1), dim3(64), 0, stream,
                       rW1, rb1, rg1, rW2, rb2, rg2, rW3, rb3, table);
    hipLaunchKernelGGL(k1_fused, dim3(Bn * Nn), dim3(256), 0, stream,
                       atoms, rel, adj, mask, soft, ntab, table,
                       atab, nW1, nb1, ng, nW2, nb2, out);
}